// Round 7
// baseline (2189.730 us; speedup 1.0000x reference)
//
#include <hip/hip_runtime.h>
#include <math.h>

// B=8192, C=4, D=256, E=8, H=256, O=128, AQ=18, HQ=512, N=B*C=32768
//
// fp16-split (Ozaki) MFMA: v = hi + lo*2^-12, 3 MFMAs per product pair,
// fp32 accumulation -> ~2^-22 relative error, safe for co0>THRESH gates.
// R6 restructure (barrier-bound diagnosis; R5 pipelining was neutral):
//  - GEMM1 computed TRANSPOSED: A=We1 frags (same arrays as B-major --
//    layouts coincide), B=x frags from LDS. Output h^T has token-on-lanes.
//  - h^T C-tile -> GEMM2 A-frags via in-register shfl_xor(32) half
//    exchange (no LDS round-trip, no h staging).
//  - GEMM2 K-split across the 4 waves; per-expert partials scaled by g_e
//    and accumulated in registers; be2 folded via softmax sum=1 trick.
//  - Expert loop has ZERO barriers / ZERO LDS writes. One 3-barrier tree
//    reduction at kernel end.

typedef _Float16 f16;
typedef f16   f16x8  __attribute__((ext_vector_type(8)));
typedef f16   f16x4  __attribute__((ext_vector_type(4)));
typedef float f32x16 __attribute__((ext_vector_type(16)));
typedef float v4f    __attribute__((ext_vector_type(4)));
typedef unsigned int v4u __attribute__((ext_vector_type(4)));

#define MFMA(a, b, c) __builtin_amdgcn_mfma_f32_32x32x16_f16(a, b, c, 0, 0, 0)
#define LO_SCALE 4096.0f
#define LO_INV   (1.0f / 4096.0f)

#define XS 264   // f16 stride of 256-wide LDS rows (528B, 16B-aligned)
#define RS 136   // f16 stride of 128-wide LDS rows
#define QS 520   // f16 stride of 512-wide LDS rows (q kernel)

__device__ __forceinline__ v4f nt_load4(const float* p) {
    return __builtin_nontemporal_load((const v4f*)p);
}
__device__ __forceinline__ f16x8 ldg8(const f16* p) {
    return *(const f16x8*)p;
}
__device__ __forceinline__ unsigned f16pack(f16 h, f16 l) {
    union { f16 f; unsigned short s; } a, b;
    a.f = h; b.f = l;
    return (unsigned)a.s | ((unsigned)b.s << 16);
}

// ---------------- weight prep: fp32 -> frag-major fp16 hi/lo ----------------
// One 64-lane wave per 32n x 16k fragment tile. B[k][n]: n = lane&31,
// k = (lane>>5)*8 + j. Store: tile*512 + lane*8 + j.
// (Note: for We1 this doubles as the A-major layout -- A[m][k] with
//  m=lane&31, k=(lane>>5)*8+j indexes the same We1[d][h] values.)
__global__ __launch_bounds__(256) void prep_kernel(
    const float* __restrict__ We1, const float* __restrict__ We2,
    const float* __restrict__ Wr,  const float* __restrict__ Wg,
    const float* __restrict__ Wq1, const float* __restrict__ Wq2,
    f16* __restrict__ W1H, f16* __restrict__ W1L,
    f16* __restrict__ W2H, f16* __restrict__ W2L,
    f16* __restrict__ WrH, f16* __restrict__ WrL,
    f16* __restrict__ WgH, f16* __restrict__ WgL,
    f16* __restrict__ Wq1H, f16* __restrict__ Wq1L,
    f16* __restrict__ Wq2H, f16* __restrict__ Wq2L)
{
    int t = blockIdx.x * 4 + (threadIdx.x >> 6);
    int lane = threadIdx.x & 63;
    const float* src; f16 *dh, *dl;
    int stride, ncols, kbase, nbase, tile;
    if (t < 1024) {        // We1: (E,256,256) -> 8e x 16kt x 8nt
        int e = t >> 7, kt = (t >> 3) & 15, nt = t & 7;
        src = We1 + e * 65536; stride = 256; ncols = 256;
        kbase = kt * 16; nbase = nt * 32; tile = t; dh = W1H; dl = W1L;
    } else if (t < 1536) { // We2: (E,256,128) -> 8e x 16kt x 4nt
        int i = t - 1024; int e = i >> 6, kt = (i >> 2) & 15, nt = i & 3;
        src = We2 + e * 32768; stride = 128; ncols = 128;
        kbase = kt * 16; nbase = nt * 32; tile = i; dh = W2H; dl = W2L;
    } else if (t < 1600) { // Wr: (128,256) -> 8kt x 8nt
        int i = t - 1536; int kt = i >> 3, nt = i & 7;
        src = Wr; stride = 256; ncols = 256;
        kbase = kt * 16; nbase = nt * 32; tile = i; dh = WrH; dl = WrL;
    } else if (t < 1616) { // Wg: (256,8) pad n->32 -> 16kt x 1nt
        int i = t - 1600;
        src = Wg; stride = 8; ncols = 8;
        kbase = i * 16; nbase = 0; tile = i; dh = WgH; dl = WgL;
    } else if (t < 2128) { // Wq1: (512,512) -> 32kt x 16nt
        int i = t - 1616; int kt = i >> 4, nt = i & 15;
        src = Wq1; stride = 512; ncols = 512;
        kbase = kt * 16; nbase = nt * 32; tile = i; dh = Wq1H; dl = Wq1L;
    } else {               // Wq2: (512,18) pad n->32 -> 32kt x 1nt
        int i = t - 2128;
        src = Wq2; stride = 18; ncols = 18;
        kbase = i * 16; nbase = 0; tile = i; dh = Wq2H; dl = Wq2L;
    }
    int n = lane & 31, kg = lane >> 5;
    int col = nbase + n;
    f16x8 hv, lv;
    #pragma unroll
    for (int j = 0; j < 8; ++j) {
        int k = kbase + kg * 8 + j;
        float w = (col < ncols) ? src[(size_t)k * stride + col] : 0.f;
        f16 h = (f16)w;
        hv[j] = h;
        lv[j] = (f16)((w - (float)h) * LO_SCALE);
    }
    *(f16x8*)(dh + (size_t)tile * 512 + lane * 8) = hv;
    *(f16x8*)(dl + (size_t)tile * 512 + lane * 8) = lv;
}

// ---------------- fused MoE kernel (MFMA, barrier-free expert loop) --------
// 32 tokens/block, 256 threads = 4 waves, 1024 blocks, 2 blocks/CU.
template<bool REC>
__global__ __launch_bounds__(256, 2) void moe_mfma(
    const float* xsrc, const float* __restrict__ sbuf,
    const f16* __restrict__ W1H, const f16* __restrict__ W1L,
    const f16* __restrict__ W2H, const f16* __restrict__ W2L,
    const f16* __restrict__ WrH, const f16* __restrict__ WrL,
    const f16* __restrict__ WgH, const f16* __restrict__ WgL,
    const float* __restrict__ be1, const float* __restrict__ be2,
    const float* __restrict__ bg,  const float* __restrict__ br,
    float* result)
{
    extern __shared__ char smem[];
    f16* xh = (f16*)smem;                    // [32][XS]
    f16* xl = xh + 32 * XS;
    float* red = (float*)(xl + 32 * XS);     // 8192 f32 (32KB); also REC r-stage

    const int tid = threadIdx.x;
    const int lane = tid & 63;
    const int wv = tid >> 6;                 // 0..3
    const int l31 = lane & 31;
    const int kg = lane >> 5;
    const int n0 = blockIdx.x * 32;

    if (!REC) {
        // stage x (32x256 fp32) -> split hi/lo rows [token][d]
        #pragma unroll
        for (int i = 0; i < 8; ++i) {
            int idx = i * 256 + tid;
            int m = idx >> 6, k4 = (idx & 63) * 4;
            v4f v = nt_load4(&xsrc[(size_t)(n0 + m) * 256 + k4]);
            f16x4 hv, lv;
            #pragma unroll
            for (int j = 0; j < 4; ++j) {
                hv[j] = (f16)v[j];
                lv[j] = (f16)((v[j] - (float)hv[j]) * LO_SCALE);
            }
            *(f16x4*)&xh[m * XS + k4] = hv;
            *(f16x4*)&xl[m * XS + k4] = lv;
        }
    } else {
        // stage r (32x128) hi/lo at RS stride into red region
        f16* rh = (f16*)red;
        f16* rl = rh + 32 * RS;
        #pragma unroll
        for (int i = 0; i < 4; ++i) {
            int idx = i * 256 + tid;
            int m = idx >> 5, k4 = (idx & 31) * 4;
            v4f v = nt_load4(&xsrc[(size_t)(n0 + m) * 128 + k4]);
            f16x4 hv, lv;
            #pragma unroll
            for (int j = 0; j < 4; ++j) {
                hv[j] = (f16)v[j];
                lv[j] = (f16)((v[j] - (float)hv[j]) * LO_SCALE);
            }
            *(f16x4*)&rh[m * RS + k4] = hv;
            *(f16x4*)&rl[m * RS + k4] = lv;
        }
        __syncthreads();
        // rec GEMM: x(32x256) = r(32x128) @ Wr + br; wave w -> nt {2w,2w+1}
        f32x16 am0 = {}, a0a = {}, a0b = {}, am1 = {}, a1a = {}, a1b = {};
        const f16* wrh = WrH + (size_t)(2 * wv) * 512 + lane * 8;
        const f16* wrl = WrL + (size_t)(2 * wv) * 512 + lane * 8;
        #pragma unroll
        for (int kt = 0; kt < 8; ++kt) {
            f16x8 b0h = ldg8(wrh + (size_t)kt * 4096);
            f16x8 b0l = ldg8(wrl + (size_t)kt * 4096);
            f16x8 b1h = ldg8(wrh + (size_t)kt * 4096 + 512);
            f16x8 b1l = ldg8(wrl + (size_t)kt * 4096 + 512);
            f16x8 ah = *(const f16x8*)&rh[l31 * RS + kt * 16 + kg * 8];
            f16x8 al = *(const f16x8*)&rl[l31 * RS + kt * 16 + kg * 8];
            am0 = MFMA(ah, b0h, am0); a0a = MFMA(al, b0h, a0a); a0b = MFMA(ah, b0l, a0b);
            am1 = MFMA(ah, b1h, am1); a1a = MFMA(al, b1h, a1a); a1b = MFMA(ah, b1l, a1b);
        }
        #pragma unroll
        for (int t = 0; t < 2; ++t) {
            int col = (2 * wv + t) * 32 + l31;
            float brv = br[col];
            #pragma unroll
            for (int r = 0; r < 16; ++r) {
                int row = (r & 3) + 8 * (r >> 2) + 4 * kg;
                float v = (t ? am1[r] + (a1a[r] + a1b[r]) * LO_INV
                             : am0[r] + (a0a[r] + a0b[r]) * LO_INV) + brv;
                f16 hv = (f16)v;
                xh[row * XS + col] = hv;
                xl[row * XS + col] = (f16)((v - (float)hv) * LO_SCALE);
            }
        }
    }
    __syncthreads();

    // ---- gating (all waves redundant): logits = x @ Wg + bg ----
    // C: row=token, col=e(=l31<8). gr[r] = g[token(r,kg)][e=l31].
    float gr[16];
    {
        f32x16 gm = {}, ga = {}, gb = {};
        #pragma unroll
        for (int kt = 0; kt < 16; ++kt) {
            f16x8 ah = *(const f16x8*)&xh[l31 * XS + kt * 16 + kg * 8];
            f16x8 al = *(const f16x8*)&xl[l31 * XS + kt * 16 + kg * 8];
            f16x8 bh = ldg8(WgH + (size_t)kt * 512 + lane * 8);
            f16x8 bl = ldg8(WgL + (size_t)kt * 512 + lane * 8);
            gm = MFMA(ah, bh, gm); ga = MFMA(al, bh, ga); gb = MFMA(ah, bl, gb);
        }
        float bge = (l31 < 8) ? bg[l31] : 0.f;
        #pragma unroll
        for (int r = 0; r < 16; ++r) {
            float lg = gm[r] + (ga[r] + gb[r]) * LO_INV + bge;
            float mx = lg;
            #pragma unroll
            for (int d = 1; d < 8; d <<= 1) mx = fmaxf(mx, __shfl_xor(mx, d, 64));
            float ex = __expf(lg - mx);
            float s = ex;
            #pragma unroll
            for (int d = 1; d < 8; d <<= 1) s += __shfl_xor(s, d, 64);
            gr[r] = ex / s;
        }
    }

    // ---- expert loop (NO barriers) ----
    // out[nt]: K-partial of sum_e g_e*eo_e over this wave's h k-slice.
    f32x16 out[4] = {};
    #pragma unroll 1
    for (int e = 0; e < 8; ++e) {
        // GEMM1 transposed: h^T(2 tiles of 32H x 32tok) = We1^T @ x^T
        // A = We1 frags (m=h-col on lanes), B = x frags (n=token on lanes).
        f32x16 am0 = {}, a0a = {}, a0b = {}, am1 = {}, a1a = {}, a1b = {};
        const f16* w1h = W1H + (size_t)e * 65536 + (2 * wv) * 512 + lane * 8;
        const f16* w1l = W1L + (size_t)e * 65536 + (2 * wv) * 512 + lane * 8;
        #pragma unroll
        for (int kt = 0; kt < 16; ++kt) {
            f16x8 a0h = ldg8(w1h + (size_t)kt * 4096);
            f16x8 a0l = ldg8(w1l + (size_t)kt * 4096);
            f16x8 a1h = ldg8(w1h + (size_t)kt * 4096 + 512);
            f16x8 a1l = ldg8(w1l + (size_t)kt * 4096 + 512);
            f16x8 bh = *(const f16x8*)&xh[l31 * XS + kt * 16 + kg * 8];
            f16x8 bl = *(const f16x8*)&xl[l31 * XS + kt * 16 + kg * 8];
            am0 = MFMA(a0h, bh, am0); a0a = MFMA(a0l, bh, a0a); a0b = MFMA(a0h, bl, a0b);
            am1 = MFMA(a1h, bh, am1); a1a = MFMA(a1l, bh, a1a); a1b = MFMA(a1h, bl, a1b);
        }
        // epilogue in regs: fold + be1 + relu + split/pack (hi|lo in u32)
        unsigned pk0[16], pk1[16];
        #pragma unroll
        for (int r = 0; r < 16; ++r) {
            int rho = (r & 3) + 8 * (r >> 2) + 4 * kg;
            float v0 = am0[r] + (a0a[r] + a0b[r]) * LO_INV
                       + be1[e * 256 + 64 * wv + rho];
            v0 = fmaxf(v0, 0.f);
            f16 h0 = (f16)v0;
            pk0[r] = f16pack(h0, (f16)((v0 - (float)h0) * LO_SCALE));
            float v1 = am1[r] + (a1a[r] + a1b[r]) * LO_INV
                       + be1[e * 256 + 64 * wv + 32 + rho];
            v1 = fmaxf(v1, 0.f);
            f16 h1 = (f16)v1;
            pk1[r] = f16pack(h1, (f16)((v1 - (float)h1) * LO_SCALE));
        }
        // build GEMM2 A-frags: k = 64w + 16*t2l + 8*kg + j, m = token = l31.
        // j<4 from kg==0 half, j>=4 from kg==1 half, reg = (j&3)+8*ktl+4*kg_d.
        f16x8 A2h[4], A2l[4];
        #pragma unroll
        for (int t2l = 0; t2l < 4; ++t2l) {
            const unsigned* pk = (t2l >> 1) ? pk1 : pk0;
            int ktl = t2l & 1;
            unsigned jl[4], jh[4];
            #pragma unroll
            for (int c = 0; c < 4; ++c) {
                unsigned pa = pk[c + 8 * ktl];
                unsigned pb = pk[c + 8 * ktl + 4];
                unsigned sa = (unsigned)__shfl_xor((int)pa, 32, 64);
                unsigned sb = (unsigned)__shfl_xor((int)pb, 32, 64);
                jl[c] = kg ? sb : pa;
                jh[c] = kg ? pb : sa;
            }
            v4u wh, wl;
            wh[0] = (jl[0] & 0xffffu) | (jl[1] << 16);
            wh[1] = (jl[2] & 0xffffu) | (jl[3] << 16);
            wh[2] = (jh[0] & 0xffffu) | (jh[1] << 16);
            wh[3] = (jh[2] & 0xffffu) | (jh[3] << 16);
            wl[0] = (jl[0] >> 16) | (jl[1] & 0xffff0000u);
            wl[1] = (jl[2] >> 16) | (jl[3] & 0xffff0000u);
            wl[2] = (jh[0] >> 16) | (jh[1] & 0xffff0000u);
            wl[3] = (jh[2] >> 16) | (jh[3] & 0xffff0000u);
            A2h[t2l] = __builtin_bit_cast(f16x8, wh);
            A2l[t2l] = __builtin_bit_cast(f16x8, wl);
        }
        // g for this expert, per token-row r (same C row map as GEMM2 out)
        float ge[16];
        #pragma unroll
        for (int r = 0; r < 16; ++r)
            ge[r] = __shfl(gr[r], (lane & 32) + e, 64);
        // GEMM2 K-split: this wave's k-slice = t2 in {4w..4w+3}; all 4 nt.
        #pragma unroll
        for (int nt = 0; nt < 4; ++nt) {
            f32x16 cm = {}, ca = {}, cb = {};
            const f16* w2h = W2H + (size_t)e * 32768 + (size_t)(4 * wv * 4 + nt) * 512
                             + lane * 8;
            const f16* w2l = W2L + (size_t)e * 32768 + (size_t)(4 * wv * 4 + nt) * 512
                             + lane * 8;
            #pragma unroll
            for (int t2l = 0; t2l < 4; ++t2l) {
                f16x8 bh = ldg8(w2h + (size_t)t2l * 2048);
                f16x8 bl = ldg8(w2l + (size_t)t2l * 2048);
                cm = MFMA(A2h[t2l], bh, cm);
                ca = MFMA(A2l[t2l], bh, ca);
                cb = MFMA(A2h[t2l], bl, cb);
            }
            float be2v = (wv == 0) ? be2[e * 128 + nt * 32 + l31] : 0.f;
            #pragma unroll
            for (int r = 0; r < 16; ++r) {
                float tmp = cm[r] + (ca[r] + cb[r]) * LO_INV + be2v;
                out[nt][r] += ge[r] * tmp;
            }
        }
    }

    // ---- cross-wave K-reduction (3 barriers) + store ----
    if (wv >= 2) {
        float* dst = red + (wv - 2) * 4096;
        #pragma unroll
        for (int nt = 0; nt < 4; ++nt)
            #pragma unroll
            for (int r = 0; r < 16; ++r)
                dst[nt * 1024 + r * 64 + lane] = out[nt][r];
    }
    __syncthreads();
    if (wv < 2) {
        const float* src = red + wv * 4096;
        #pragma unroll
        for (int nt = 0; nt < 4; ++nt)
            #pragma unroll
            for (int r = 0; r < 16; ++r)
                out[nt][r] += src[nt * 1024 + r * 64 + lane];
    }
    __syncthreads();
    if (wv == 0) {
        #pragma unroll
        for (int nt = 2; nt < 4; ++nt)
            #pragma unroll
            for (int r = 0; r < 16; ++r)
                red[(nt - 2) * 1024 + r * 64 + lane] = out[nt][r];
    } else if (wv == 1) {
        #pragma unroll
        for (int nt = 0; nt < 2; ++nt)
            #pragma unroll
            for (int r = 0; r < 16; ++r)
                red[2048 + nt * 1024 + r * 64 + lane] = out[nt][r];
    }
    __syncthreads();
    if (wv < 2) {
        #pragma unroll
        for (int q = 0; q < 2; ++q) {
            int nt = wv * 2 + q;
            const float* src = (wv == 0) ? (red + 2048 + nt * 1024)
                                         : (red + (nt - 2) * 1024);
            #pragma unroll
            for (int r = 0; r < 16; ++r) {
                int row = (r & 3) + 8 * (r >> 2) + 4 * kg;
                size_t off = (size_t)(n0 + row) * 128 + nt * 32 + l31;
                float v = out[nt][r] + src[r * 64 + lane];
                if (REC) {
                    float sv = sbuf[(n0 + row) >> 2];
                    float old = __builtin_nontemporal_load(&result[off]);
                    v = old + v * sv;
                }
                __builtin_nontemporal_store(v, &result[off]);
            }
        }
    }
}

// ---------------- co / gate kernel (fp32 VALU, tiny) ----------------
__global__ __launch_bounds__(256) void co_kernel(
    const float* __restrict__ result, const float* __restrict__ Wog,
    const float* __restrict__ bog, float* __restrict__ sbuf, float thresh)
{
    int lane = threadIdx.x & 63;
    int w = threadIdx.x >> 6;
    int b = blockIdx.x * 4 + w;
    const float* r = result + (size_t)b * 512;
    float l0 = 0.f, l1 = 0.f;
    #pragma unroll
    for (int j = 0; j < 8; ++j) {
        int d = j * 64 + lane;
        float rv = __builtin_nontemporal_load(&r[d]);
        float2 wv = *(const float2*)&Wog[d * 2];
        l0 = fmaf(rv, wv.x, l0);
        l1 = fmaf(rv, wv.y, l1);
    }
    #pragma unroll
    for (int off = 32; off > 0; off >>= 1) {
        l0 += __shfl_down(l0, off);
        l1 += __shfl_down(l1, off);
    }
    if (lane == 0) {
        l0 += bog[0]; l1 += bog[1];
        float co0 = 1.f / (1.f + __expf(l1 - l0));
        sbuf[b] = (co0 > thresh) ? co0 : 0.f;
    }
}

// ---------------- Q head kernel (MFMA) ----------------
// 32 samples/block, 512 threads. values = relu(result@Wq1+bq1)@Wq2+bq2
__global__ __launch_bounds__(512, 2) void q_mfma(
    const float* __restrict__ result,
    const f16* __restrict__ Wq1H, const f16* __restrict__ Wq1L,
    const f16* __restrict__ Wq2H, const f16* __restrict__ Wq2L,
    const float* __restrict__ bq1, const float* __restrict__ bq2,
    float* __restrict__ out)
{
    extern __shared__ char smem[];
    f16* rh = (f16*)smem;              // [32][QS]
    f16* rl = rh + 32 * QS;
    f16* hh = rl + 32 * QS;
    f16* hl = hh + 32 * QS;
    float* part = (float*)(hl + 32 * QS);  // [4][1024]
    const int tid = threadIdx.x;
    const int lane = tid & 63;
    const int wv = tid >> 6;
    const int l31 = lane & 31;
    const int kg = lane >> 5;
    const int n0 = blockIdx.x * 32;

    // stage result rows (32x512) hi/lo
    #pragma unroll
    for (int i = 0; i < 8; ++i) {
        int idx = i * 512 + tid;
        int m = idx >> 7, k4 = (idx & 127) * 4;
        v4f v = nt_load4(&result[(size_t)(n0 + m) * 512 + k4]);
        f16x4 hv, lv;
        #pragma unroll
        for (int j = 0; j < 4; ++j) {
            hv[j] = (f16)v[j];
            lv[j] = (f16)((v[j] - (float)hv[j]) * LO_SCALE);
        }
        *(f16x4*)&rh[m * QS + k4] = hv;
        *(f16x4*)&rl[m * QS + k4] = lv;
    }
    __syncthreads();

    // GEMM1: hid(32x512) = relu(r @ Wq1 + bq1); 16 Ntiles / 8 waves
    f32x16 am0 = {}, ac0 = {}, am1 = {}, ac1 = {};
    const int nt0 = wv * 2;
    #pragma unroll
    for (int kt = 0; kt < 32; ++kt) {
        f16x8 ah = *(const f16x8*)&rh[l31 * QS + kt * 16 + kg * 8];
        f16x8 al = *(const f16x8*)&rl[l31 * QS + kt * 16 + kg * 8];
        f16x8 b0h = ldg8(Wq1H + (size_t)(kt * 16 + nt0) * 512 + lane * 8);
        f16x8 b0l = ldg8(Wq1L + (size_t)(kt * 16 + nt0) * 512 + lane * 8);
        f16x8 b1h = ldg8(Wq1H + (size_t)(kt * 16 + nt0 + 1) * 512 + lane * 8);
        f16x8 b1l = ldg8(Wq1L + (size_t)(kt * 16 + nt0 + 1) * 512 + lane * 8);
        am0 = MFMA(ah, b0h, am0); ac0 = MFMA(al, b0h, ac0); ac0 = MFMA(ah, b0l, ac0);
        am1 = MFMA(ah, b1h, am1); ac1 = MFMA(al, b1h, ac1); ac1 = MFMA(ah, b1l, ac1);
    }
    #pragma unroll
    for (int t = 0; t < 2; ++t) {
        int col = (nt0 + t) * 32 + l31;
        float b1v = bq1[col];
        #pragma unroll
        for (int r = 0; r < 16; ++r) {
            int row = (r & 3) + 8 * (r >> 2) + 4 * kg;
            float v = (t ? am1[r] + ac1[r] * LO_INV : am0[r] + ac0[r] * LO_INV) + b1v;
            v = fmaxf(v, 0.f);
            f16 hv = (f16)v;
            hh[row * QS + col] = hv;
            hl[row * QS + col] = (f16)((v - (float)hv) * LO_SCALE);
        }
    }
    __syncthreads();

    // GEMM2: values(32x18) = hid @ Wq2 + bq2; K split over waves 0-3
    if (wv < 4) {
        f32x16 am = {}, ac = {};
        #pragma unroll
        for (int k2 = 0; k2 < 8; ++k2) {
            int kt = wv * 8 + k2;
            f16x8 ah = *(const f16x8*)&hh[l31 * QS + kt * 16 + kg * 8];
            f16x8 al = *(const f16x8*)&hl[l31 * QS + kt * 16 + kg * 8];
            f16x8 bh = ldg8(Wq2H + (size_t)kt * 512 + lane * 8);
            f16x8 bl = ldg8(Wq2L + (size_t)kt * 512 + lane * 8);
            am = MFMA(ah, bh, am); ac = MFMA(al, bh, ac); ac = MFMA(ah, bl, ac);
        }
        #pragma unroll
        for (int r = 0; r < 16; ++r) {
            int row = (r & 3) + 8 * (r >> 2) + 4 * kg;
            part[wv * 1024 + row * 32 + l31] = am[r] + ac[r] * LO_INV;
        }
    }
    __syncthreads();
    for (int idx = tid; idx < 1024; idx += 512) {
        int row = idx >> 5, c = idx & 31;
        if (c < 18) {
            float s = part[idx] + part[1024 + idx] + part[2048 + idx] + part[3072 + idx]
                      + bq2[c];
            out[(size_t)(n0 + row) * 18 + c] = s;
        }
    }
}

extern "C" void kernel_launch(void* const* d_in, const int* in_sizes, int n_in,
                              void* d_out, int out_size, void* d_ws, size_t ws_size,
                              hipStream_t stream)
{
    (void)in_sizes; (void)n_in; (void)out_size; (void)ws_size;
    const float* data = (const float*)d_in[0];
    const float* We1  = (const float*)d_in[1];
    const float* be1  = (const float*)d_in[2];
    const float* We2  = (const float*)d_in[3];
    const float* be2  = (const float*)d_in[4];
    const float* Wg   = (const float*)d_in[5];
    const float* bg   = (const float*)d_in[6];
    const float* Wog  = (const float*)d_in[7];
    const float* bog  = (const float*)d_in[8];
    const float* Wr   = (const float*)d_in[9];
    const float* br   = (const float*)d_in[10];
    const float* Wq1  = (const float*)d_in[11];
    const float* bq1  = (const float*)d_in[12];
    const float* Wq2  = (const float*)d_in[13];
    const float* bq2  = (const float*)d_in[14];
    float* outp = (float*)d_out;

    float* result = (float*)d_ws;                         // 32768*128 fp32
    float* sbuf   = result + (size_t)32768 * 128;         // 8192 fp32
    f16* fb = (f16*)((char*)d_ws + 16809984);             // frag arrays base
    f16* W1H  = fb;
    f16* W1L  = fb + 524288;
    f16* W2H  = fb + 1048576;
    f16* W2L  = fb + 1310720;
    f16* WrH  = fb + 1572864;
    f16* WrL  = fb + 1605632;
    f16* WgH  = fb + 1638400;
    f16* WgL  = fb + 1646592;
    f16* Wq1H = fb + 1654784;
    f16* Wq1L = fb + 1916928;
    f16* Wq2H = fb + 2179072;
    f16* Wq2L = fb + 2195456;

    const int MOE_LDS = 2 * 32 * XS * 2 + 32768;          // 66560 B
    const int Q_LDS   = 4 * 32 * QS * 2 + 4 * 1024 * 4;   // 149504 B

    prep_kernel<<<540, 256, 0, stream>>>(We1, We2, Wr, Wg, Wq1, Wq2,
        W1H, W1L, W2H, W2L, WrH, WrL, WgH, WgL, Wq1H, Wq1L, Wq2H, Wq2L);

    moe_mfma<false><<<1024, 256, MOE_LDS, stream>>>(
        data, nullptr, W1H, W1L, W2H, W2L, WrH, WrL, WgH, WgL,
        be1, be2, bg, br, result);
    co_kernel<<<2048, 256, 0, stream>>>(result, Wog, bog, sbuf, 0.3f);
    moe_mfma<true><<<1024, 256, MOE_LDS, stream>>>(
        result, sbuf, W1H, W1L, W2H, W2L, WrH, WrL, WgH, WgL,
        be1, be2, bg, br, result);
    co_kernel<<<2048, 256, 0, stream>>>(result, Wog, bog, sbuf, 0.5f);
    moe_mfma<true><<<1024, 256, MOE_LDS, stream>>>(
        result, sbuf, W1H, W1L, W2H, W2L, WrH, WrL, WgH, WgL,
        be1, be2, bg, br, result);
    q_mfma<<<256, 512, Q_LDS, stream>>>(result, Wq1H, Wq1L, Wq2H, Wq2L,
        bq1, bq2, outp);
}

// Round 8
// 720.476 us; speedup vs baseline: 3.0393x; 3.0393x over previous
//
#include <hip/hip_runtime.h>
#include <math.h>

// B=8192, C=4, D=256, E=8, H=256, O=128, AQ=18, HQ=512, N=B*C=32768
//
// fp16-split (Ozaki) MFMA: v = hi + lo*2^-12, 3 MFMAs per product pair,
// fp32 accumulation -> ~2^-22 relative error, safe for co0>THRESH gates.
// R7 (revert R6 spill disaster; attack latency with TLP):
//  - moe: 512 thr/block (8 waves), 32 tokens, LDS 67.6KB -> 2 blocks/CU
//    = 16 waves/CU = 4 waves/SIMD (2x TLP vs R5).
//  - per-wave work halved: GEMM1 1 N-tile/wave, GEMM2 K-split (nt=wv&3,
//    k-half=wv>>2) + one 2-way LDS reduction at the end.
//  - 2 accumulators per K-loop (serialized correction) to fit the
//    128-VGPR cap of __launch_bounds__(512,4). TLP covers dep chains.

typedef _Float16 f16;
typedef f16   f16x8  __attribute__((ext_vector_type(8)));
typedef f16   f16x4  __attribute__((ext_vector_type(4)));
typedef float f32x16 __attribute__((ext_vector_type(16)));
typedef float v4f    __attribute__((ext_vector_type(4)));

#define MFMA(a, b, c) __builtin_amdgcn_mfma_f32_32x32x16_f16(a, b, c, 0, 0, 0)
#define LO_SCALE 4096.0f
#define LO_INV   (1.0f / 4096.0f)

#define XS 264   // f16 stride of 256-wide LDS rows (528B, 16B-aligned)
#define RS 136   // f16 stride of 128-wide LDS rows
#define QS 520   // f16 stride of 512-wide LDS rows (q kernel)

__device__ __forceinline__ v4f nt_load4(const float* p) {
    return __builtin_nontemporal_load((const v4f*)p);
}
__device__ __forceinline__ f16x8 ldg8(const f16* p) {
    return *(const f16x8*)p;
}

// ---------------- weight prep: fp32 -> frag-major fp16 hi/lo ----------------
// One 64-lane wave per 32n x 16k fragment tile. B[k][n]: n = lane&31,
// k = (lane>>5)*8 + j. Store: tile*512 + lane*8 + j.
__global__ __launch_bounds__(256) void prep_kernel(
    const float* __restrict__ We1, const float* __restrict__ We2,
    const float* __restrict__ Wr,  const float* __restrict__ Wg,
    const float* __restrict__ Wq1, const float* __restrict__ Wq2,
    f16* __restrict__ W1H, f16* __restrict__ W1L,
    f16* __restrict__ W2H, f16* __restrict__ W2L,
    f16* __restrict__ WrH, f16* __restrict__ WrL,
    f16* __restrict__ WgH, f16* __restrict__ WgL,
    f16* __restrict__ Wq1H, f16* __restrict__ Wq1L,
    f16* __restrict__ Wq2H, f16* __restrict__ Wq2L)
{
    int t = blockIdx.x * 4 + (threadIdx.x >> 6);
    int lane = threadIdx.x & 63;
    const float* src; f16 *dh, *dl;
    int stride, ncols, kbase, nbase, tile;
    if (t < 1024) {        // We1: (E,256,256) -> 8e x 16kt x 8nt
        int e = t >> 7, kt = (t >> 3) & 15, nt = t & 7;
        src = We1 + e * 65536; stride = 256; ncols = 256;
        kbase = kt * 16; nbase = nt * 32; tile = t; dh = W1H; dl = W1L;
    } else if (t < 1536) { // We2: (E,256,128) -> 8e x 16kt x 4nt
        int i = t - 1024; int e = i >> 6, kt = (i >> 2) & 15, nt = i & 3;
        src = We2 + e * 32768; stride = 128; ncols = 128;
        kbase = kt * 16; nbase = nt * 32; tile = i; dh = W2H; dl = W2L;
    } else if (t < 1600) { // Wr: (128,256) -> 8kt x 8nt
        int i = t - 1536; int kt = i >> 3, nt = i & 7;
        src = Wr; stride = 256; ncols = 256;
        kbase = kt * 16; nbase = nt * 32; tile = i; dh = WrH; dl = WrL;
    } else if (t < 1616) { // Wg: (256,8) pad n->32 -> 16kt x 1nt
        int i = t - 1600;
        src = Wg; stride = 8; ncols = 8;
        kbase = i * 16; nbase = 0; tile = i; dh = WgH; dl = WgL;
    } else if (t < 2128) { // Wq1: (512,512) -> 32kt x 16nt
        int i = t - 1616; int kt = i >> 4, nt = i & 15;
        src = Wq1; stride = 512; ncols = 512;
        kbase = kt * 16; nbase = nt * 32; tile = i; dh = Wq1H; dl = Wq1L;
    } else {               // Wq2: (512,18) pad n->32 -> 32kt x 1nt
        int i = t - 2128;
        src = Wq2; stride = 18; ncols = 18;
        kbase = i * 16; nbase = 0; tile = i; dh = Wq2H; dl = Wq2L;
    }
    int n = lane & 31, kg = lane >> 5;
    int col = nbase + n;
    f16x8 hv, lv;
    #pragma unroll
    for (int j = 0; j < 8; ++j) {
        int k = kbase + kg * 8 + j;
        float w = (col < ncols) ? src[(size_t)k * stride + col] : 0.f;
        f16 h = (f16)w;
        hv[j] = h;
        lv[j] = (f16)((w - (float)h) * LO_SCALE);
    }
    *(f16x8*)(dh + (size_t)tile * 512 + lane * 8) = hv;
    *(f16x8*)(dl + (size_t)tile * 512 + lane * 8) = lv;
}

// ---------------- fused MoE kernel (MFMA) ----------------
// 32 tokens/block, 512 threads = 8 waves, 1024 blocks, 2 blocks/CU
// (16 waves/CU). GEMM1/rec: wave w -> N-tile w. GEMM2: nt=wv&3, K-half
// kh=wv>>2; 2-way reduction at end. Gating redundant per wave (g via shfl).
template<bool REC>
__global__ __launch_bounds__(512, 4) void moe_mfma(
    const float* xsrc, const float* __restrict__ sbuf,
    const f16* __restrict__ W1H, const f16* __restrict__ W1L,
    const f16* __restrict__ W2H, const f16* __restrict__ W2L,
    const f16* __restrict__ WrH, const f16* __restrict__ WrL,
    const f16* __restrict__ WgH, const f16* __restrict__ WgL,
    const float* __restrict__ be1, const float* __restrict__ be2,
    const float* __restrict__ bg,  const float* __restrict__ br,
    float* result)
{
    extern __shared__ char smem[];
    f16* xh = (f16*)smem;              // [32][XS]
    f16* xl = xh + 32 * XS;
    f16* hh = xl + 32 * XS;            // [32][XS]; REC r-stage; final red
    f16* hl = hh + 32 * XS;

    const int tid = threadIdx.x;
    const int lane = tid & 63;
    const int wv = tid >> 6;           // 0..7
    const int l31 = lane & 31;
    const int kg = lane >> 5;
    const int n0 = blockIdx.x * 32;
    const int nt2 = wv & 3, kh = wv >> 2;

    if (!REC) {
        // stage x (32x256 fp32) -> split hi/lo rows
        #pragma unroll
        for (int i = 0; i < 4; ++i) {
            int idx = i * 512 + tid;
            int m = idx >> 6, k4 = (idx & 63) * 4;
            v4f v = nt_load4(&xsrc[(size_t)(n0 + m) * 256 + k4]);
            f16x4 hv, lv;
            #pragma unroll
            for (int j = 0; j < 4; ++j) {
                hv[j] = (f16)v[j];
                lv[j] = (f16)((v[j] - (float)hv[j]) * LO_SCALE);
            }
            *(f16x4*)&xh[m * XS + k4] = hv;
            *(f16x4*)&xl[m * XS + k4] = lv;
        }
    } else {
        // stage r (32x128) hi/lo at RS stride into hh/hl
        f16* rh = hh;
        f16* rl = hl;
        #pragma unroll
        for (int i = 0; i < 2; ++i) {
            int idx = i * 512 + tid;
            int m = idx >> 5, k4 = (idx & 31) * 4;
            v4f v = nt_load4(&xsrc[(size_t)(n0 + m) * 128 + k4]);
            f16x4 hv, lv;
            #pragma unroll
            for (int j = 0; j < 4; ++j) {
                hv[j] = (f16)v[j];
                lv[j] = (f16)((v[j] - (float)hv[j]) * LO_SCALE);
            }
            *(f16x4*)&rh[m * RS + k4] = hv;
            *(f16x4*)&rl[m * RS + k4] = lv;
        }
        __syncthreads();
        // rec GEMM: x(32x256) = r(32x128) @ Wr + br; wave w -> nt=w
        f32x16 am = {}, ac = {};
        const f16* wrh = WrH + (size_t)wv * 512 + lane * 8;
        const f16* wrl = WrL + (size_t)wv * 512 + lane * 8;
        #pragma unroll
        for (int kt = 0; kt < 8; ++kt) {
            f16x8 bh = ldg8(wrh + (size_t)kt * 4096);
            f16x8 bl = ldg8(wrl + (size_t)kt * 4096);
            f16x8 ah = *(const f16x8*)&rh[l31 * RS + kt * 16 + kg * 8];
            f16x8 al = *(const f16x8*)&rl[l31 * RS + kt * 16 + kg * 8];
            am = MFMA(ah, bh, am); ac = MFMA(al, bh, ac); ac = MFMA(ah, bl, ac);
        }
        {
            int col = wv * 32 + l31;
            float brv = br[col];
            #pragma unroll
            for (int r = 0; r < 16; ++r) {
                int row = (r & 3) + 8 * (r >> 2) + 4 * kg;
                float v = am[r] + ac[r] * LO_INV + brv;
                f16 hv = (f16)v;
                xh[row * XS + col] = hv;
                xl[row * XS + col] = (f16)((v - (float)hv) * LO_SCALE);
            }
        }
    }
    __syncthreads();

    // ---- gating (all waves redundant): logits = x @ Wg + bg ----
    float gr[16];
    {
        f32x16 gm = {}, gc = {};
        #pragma unroll
        for (int kt = 0; kt < 16; ++kt) {
            f16x8 bh = ldg8(WgH + (size_t)kt * 512 + lane * 8);
            f16x8 bl = ldg8(WgL + (size_t)kt * 512 + lane * 8);
            f16x8 ah = *(const f16x8*)&xh[l31 * XS + kt * 16 + kg * 8];
            f16x8 al = *(const f16x8*)&xl[l31 * XS + kt * 16 + kg * 8];
            gm = MFMA(ah, bh, gm); gc = MFMA(al, bh, gc); gc = MFMA(ah, bl, gc);
        }
        float bge = (l31 < 8) ? bg[l31] : 0.f;
        #pragma unroll
        for (int r = 0; r < 16; ++r) {
            float lg = gm[r] + gc[r] * LO_INV + bge;
            float mx = lg;
            #pragma unroll
            for (int d = 1; d < 8; d <<= 1) mx = fmaxf(mx, __shfl_xor(mx, d, 64));
            float ex = __expf(lg - mx);
            float s = ex;
            #pragma unroll
            for (int d = 1; d < 8; d <<= 1) s += __shfl_xor(s, d, 64);
            gr[r] = ex / s;   // valid on lanes l31<8 (e=l31)
        }
    }

    // ---- expert loop ----
    f32x16 out = {};
    #pragma unroll 1
    for (int e = 0; e < 8; ++e) {
        // GEMM1: h(32x256) = relu(x @ We1[e] + be1[e]); wave w -> nt=w
        f32x16 am = {}, ac = {};
        const f16* w1h = W1H + (size_t)e * 65536 + (size_t)wv * 512 + lane * 8;
        const f16* w1l = W1L + (size_t)e * 65536 + (size_t)wv * 512 + lane * 8;
        #pragma unroll
        for (int kt = 0; kt < 16; ++kt) {
            f16x8 bh = ldg8(w1h + (size_t)kt * 4096);
            f16x8 bl = ldg8(w1l + (size_t)kt * 4096);
            f16x8 ah = *(const f16x8*)&xh[l31 * XS + kt * 16 + kg * 8];
            f16x8 al = *(const f16x8*)&xl[l31 * XS + kt * 16 + kg * 8];
            am = MFMA(ah, bh, am); ac = MFMA(al, bh, ac); ac = MFMA(ah, bl, ac);
        }
        __syncthreads();   // previous GEMM2 / r-stage readers of hh/hl done
        {
            int col = wv * 32 + l31;
            float b1v = be1[e * 256 + col];
            #pragma unroll
            for (int r = 0; r < 16; ++r) {
                int row = (r & 3) + 8 * (r >> 2) + 4 * kg;
                float v = am[r] + ac[r] * LO_INV + b1v;
                v = fmaxf(v, 0.f);
                f16 hv = (f16)v;
                hh[row * XS + col] = hv;
                hl[row * XS + col] = (f16)((v - (float)hv) * LO_SCALE);
            }
        }
        __syncthreads();
        // GEMM2: eo(32x128) = h @ We2[e]; K-half kh, N-tile nt2
        f32x16 am2 = {}, ac2 = {};
        const f16* w2h = W2H + (size_t)e * 32768 + (size_t)nt2 * 512 + lane * 8;
        const f16* w2l = W2L + (size_t)e * 32768 + (size_t)nt2 * 512 + lane * 8;
        #pragma unroll
        for (int k2 = 0; k2 < 8; ++k2) {
            int kt = kh * 8 + k2;
            f16x8 bh = ldg8(w2h + (size_t)kt * 2048);
            f16x8 bl = ldg8(w2l + (size_t)kt * 2048);
            f16x8 ah = *(const f16x8*)&hh[l31 * XS + kt * 16 + kg * 8];
            f16x8 al = *(const f16x8*)&hl[l31 * XS + kt * 16 + kg * 8];
            am2 = MFMA(ah, bh, am2); ac2 = MFMA(al, bh, ac2); ac2 = MFMA(ah, bl, ac2);
        }
        float be2v = (kh == 0) ? be2[e * 128 + nt2 * 32 + l31] : 0.f;
        #pragma unroll
        for (int r = 0; r < 16; ++r) {
            float eo = am2[r] + ac2[r] * LO_INV + be2v;
            float gv = __shfl(gr[r], (lane & 32) + e, 64);
            out[r] += gv * eo;
        }
    }

    // ---- 2-way K reduction (reuse hh region) + store ----
    float* red = (float*)hh;
    __syncthreads();
    if (kh == 1) {
        #pragma unroll
        for (int r = 0; r < 16; ++r)
            red[nt2 * 1024 + r * 64 + lane] = out[r];
    }
    __syncthreads();
    if (kh == 0) {
        int col = nt2 * 32 + l31;
        #pragma unroll
        for (int r = 0; r < 16; ++r) {
            int row = (r & 3) + 8 * (r >> 2) + 4 * kg;
            size_t off = (size_t)(n0 + row) * 128 + col;
            float v = out[r] + red[nt2 * 1024 + r * 64 + lane];
            if (REC) {
                float sv = sbuf[(n0 + row) >> 2];
                float old = __builtin_nontemporal_load(&result[off]);
                v = old + v * sv;
            }
            __builtin_nontemporal_store(v, &result[off]);
        }
    }
}

// ---------------- co / gate kernel (fp32 VALU, tiny) ----------------
__global__ __launch_bounds__(256) void co_kernel(
    const float* __restrict__ result, const float* __restrict__ Wog,
    const float* __restrict__ bog, float* __restrict__ sbuf, float thresh)
{
    int lane = threadIdx.x & 63;
    int w = threadIdx.x >> 6;
    int b = blockIdx.x * 4 + w;
    const float* r = result + (size_t)b * 512;
    float l0 = 0.f, l1 = 0.f;
    #pragma unroll
    for (int j = 0; j < 8; ++j) {
        int d = j * 64 + lane;
        float rv = __builtin_nontemporal_load(&r[d]);
        float2 wv = *(const float2*)&Wog[d * 2];
        l0 = fmaf(rv, wv.x, l0);
        l1 = fmaf(rv, wv.y, l1);
    }
    #pragma unroll
    for (int off = 32; off > 0; off >>= 1) {
        l0 += __shfl_down(l0, off);
        l1 += __shfl_down(l1, off);
    }
    if (lane == 0) {
        l0 += bog[0]; l1 += bog[1];
        float co0 = 1.f / (1.f + __expf(l1 - l0));
        sbuf[b] = (co0 > thresh) ? co0 : 0.f;
    }
}

// ---------------- Q head kernel (MFMA) ----------------
// 32 samples/block, 512 threads. values = relu(result@Wq1+bq1)@Wq2+bq2
__global__ __launch_bounds__(512, 2) void q_mfma(
    const float* __restrict__ result,
    const f16* __restrict__ Wq1H, const f16* __restrict__ Wq1L,
    const f16* __restrict__ Wq2H, const f16* __restrict__ Wq2L,
    const float* __restrict__ bq1, const float* __restrict__ bq2,
    float* __restrict__ out)
{
    extern __shared__ char smem[];
    f16* rh = (f16*)smem;              // [32][QS]
    f16* rl = rh + 32 * QS;
    f16* hh = rl + 32 * QS;
    f16* hl = hh + 32 * QS;
    float* part = (float*)(hl + 32 * QS);  // [4][1024]
    const int tid = threadIdx.x;
    const int lane = tid & 63;
    const int wv = tid >> 6;
    const int l31 = lane & 31;
    const int kg = lane >> 5;
    const int n0 = blockIdx.x * 32;

    // stage result rows (32x512) hi/lo
    #pragma unroll
    for (int i = 0; i < 8; ++i) {
        int idx = i * 512 + tid;
        int m = idx >> 7, k4 = (idx & 127) * 4;
        v4f v = nt_load4(&result[(size_t)(n0 + m) * 512 + k4]);
        f16x4 hv, lv;
        #pragma unroll
        for (int j = 0; j < 4; ++j) {
            hv[j] = (f16)v[j];
            lv[j] = (f16)((v[j] - (float)hv[j]) * LO_SCALE);
        }
        *(f16x4*)&rh[m * QS + k4] = hv;
        *(f16x4*)&rl[m * QS + k4] = lv;
    }
    __syncthreads();

    // GEMM1: hid(32x512) = relu(r @ Wq1 + bq1); 16 Ntiles / 8 waves
    f32x16 am0 = {}, ac0 = {}, am1 = {}, ac1 = {};
    const int nt0 = wv * 2;
    #pragma unroll
    for (int kt = 0; kt < 32; ++kt) {
        f16x8 ah = *(const f16x8*)&rh[l31 * QS + kt * 16 + kg * 8];
        f16x8 al = *(const f16x8*)&rl[l31 * QS + kt * 16 + kg * 8];
        f16x8 b0h = ldg8(Wq1H + (size_t)(kt * 16 + nt0) * 512 + lane * 8);
        f16x8 b0l = ldg8(Wq1L + (size_t)(kt * 16 + nt0) * 512 + lane * 8);
        f16x8 b1h = ldg8(Wq1H + (size_t)(kt * 16 + nt0 + 1) * 512 + lane * 8);
        f16x8 b1l = ldg8(Wq1L + (size_t)(kt * 16 + nt0 + 1) * 512 + lane * 8);
        am0 = MFMA(ah, b0h, am0); ac0 = MFMA(al, b0h, ac0); ac0 = MFMA(ah, b0l, ac0);
        am1 = MFMA(ah, b1h, am1); ac1 = MFMA(al, b1h, ac1); ac1 = MFMA(ah, b1l, ac1);
    }
    #pragma unroll
    for (int t = 0; t < 2; ++t) {
        int col = (nt0 + t) * 32 + l31;
        float b1v = bq1[col];
        #pragma unroll
        for (int r = 0; r < 16; ++r) {
            int row = (r & 3) + 8 * (r >> 2) + 4 * kg;
            float v = (t ? am1[r] + ac1[r] * LO_INV : am0[r] + ac0[r] * LO_INV) + b1v;
            v = fmaxf(v, 0.f);
            f16 hv = (f16)v;
            hh[row * QS + col] = hv;
            hl[row * QS + col] = (f16)((v - (float)hv) * LO_SCALE);
        }
    }
    __syncthreads();

    // GEMM2: values(32x18) = hid @ Wq2 + bq2; K split over waves 0-3
    if (wv < 4) {
        f32x16 am = {}, ac = {};
        #pragma unroll
        for (int k2 = 0; k2 < 8; ++k2) {
            int kt = wv * 8 + k2;
            f16x8 ah = *(const f16x8*)&hh[l31 * QS + kt * 16 + kg * 8];
            f16x8 al = *(const f16x8*)&hl[l31 * QS + kt * 16 + kg * 8];
            f16x8 bh = ldg8(Wq2H + (size_t)kt * 512 + lane * 8);
            f16x8 bl = ldg8(Wq2L + (size_t)kt * 512 + lane * 8);
            am = MFMA(ah, bh, am); ac = MFMA(al, bh, ac); ac = MFMA(ah, bl, ac);
        }
        #pragma unroll
        for (int r = 0; r < 16; ++r) {
            int row = (r & 3) + 8 * (r >> 2) + 4 * kg;
            part[wv * 1024 + row * 32 + l31] = am[r] + ac[r] * LO_INV;
        }
    }
    __syncthreads();
    for (int idx = tid; idx < 1024; idx += 512) {
        int row = idx >> 5, c = idx & 31;
        if (c < 18) {
            float s = part[idx] + part[1024 + idx] + part[2048 + idx] + part[3072 + idx]
                      + bq2[c];
            out[(size_t)(n0 + row) * 18 + c] = s;
        }
    }
}

extern "C" void kernel_launch(void* const* d_in, const int* in_sizes, int n_in,
                              void* d_out, int out_size, void* d_ws, size_t ws_size,
                              hipStream_t stream)
{
    (void)in_sizes; (void)n_in; (void)out_size; (void)ws_size;
    const float* data = (const float*)d_in[0];
    const float* We1  = (const float*)d_in[1];
    const float* be1  = (const float*)d_in[2];
    const float* We2  = (const float*)d_in[3];
    const float* be2  = (const float*)d_in[4];
    const float* Wg   = (const float*)d_in[5];
    const float* bg   = (const float*)d_in[6];
    const float* Wog  = (const float*)d_in[7];
    const float* bog  = (const float*)d_in[8];
    const float* Wr   = (const float*)d_in[9];
    const float* br   = (const float*)d_in[10];
    const float* Wq1  = (const float*)d_in[11];
    const float* bq1  = (const float*)d_in[12];
    const float* Wq2  = (const float*)d_in[13];
    const float* bq2  = (const float*)d_in[14];
    float* outp = (float*)d_out;

    float* result = (float*)d_ws;                         // 32768*128 fp32
    float* sbuf   = result + (size_t)32768 * 128;         // 8192 fp32
    f16* fb = (f16*)((char*)d_ws + 16809984);             // frag arrays base
    f16* W1H  = fb;
    f16* W1L  = fb + 524288;
    f16* W2H  = fb + 1048576;
    f16* W2L  = fb + 1310720;
    f16* WrH  = fb + 1572864;
    f16* WrL  = fb + 1605632;
    f16* WgH  = fb + 1638400;
    f16* WgL  = fb + 1646592;
    f16* Wq1H = fb + 1654784;
    f16* Wq1L = fb + 1916928;
    f16* Wq2H = fb + 2179072;
    f16* Wq2L = fb + 2195456;

    const int MOE_LDS = 4 * 32 * XS * 2;                  // 67584 B
    const int Q_LDS   = 4 * 32 * QS * 2 + 4 * 1024 * 4;   // 149504 B

    prep_kernel<<<540, 256, 0, stream>>>(We1, We2, Wr, Wg, Wq1, Wq2,
        W1H, W1L, W2H, W2L, WrH, WrL, WgH, WgL, Wq1H, Wq1L, Wq2H, Wq2L);

    moe_mfma<false><<<1024, 512, MOE_LDS, stream>>>(
        data, nullptr, W1H, W1L, W2H, W2L, WrH, WrL, WgH, WgL,
        be1, be2, bg, br, result);
    co_kernel<<<2048, 256, 0, stream>>>(result, Wog, bog, sbuf, 0.3f);
    moe_mfma<true><<<1024, 512, MOE_LDS, stream>>>(
        result, sbuf, W1H, W1L, W2H, W2L, WrH, WrL, WgH, WgL,
        be1, be2, bg, br, result);
    co_kernel<<<2048, 256, 0, stream>>>(result, Wog, bog, sbuf, 0.5f);
    moe_mfma<true><<<1024, 512, MOE_LDS, stream>>>(
        result, sbuf, W1H, W1L, W2H, W2L, WrH, WrL, WgH, WgL,
        be1, be2, bg, br, result);
    q_mfma<<<256, 512, Q_LDS, stream>>>(result, Wq1H, Wq1L, Wq2H, Wq2L,
        bq1, bq2, outp);
}